// Round 5
// baseline (71.558 us; speedup 1.0000x reference)
//
#include <hip/hip_runtime.h>
#include <hip/hip_bf16.h>

#define BB 2
#define SS 1024
#define DD 256
#define NCH 8           // k-chunks in attn
#define KCH 128         // k-chunk size

typedef __attribute__((ext_vector_type(8))) short bf16x8;
typedef __attribute__((ext_vector_type(4))) float f32x4;

__device__ __forceinline__ unsigned short f2bf(float f) {
    __hip_bfloat16 h = __float2bfloat16(f);
    return *reinterpret_cast<unsigned short*>(&h);
}
__device__ __forceinline__ float bf2f(unsigned short u) {
    __hip_bfloat16 h;
    *reinterpret_cast<unsigned short*>(&h) = u;
    return __bfloat162float(h);
}

// ---------------------------------------------------------------------------
// Kernel 1: QKV projection via MFMA (unchanged from round 4).
// grid = 128 rowtiles x 3 mats = 384. Block = 16 seq-rows x 256 out-cols.
// ---------------------------------------------------------------------------
__global__ __launch_bounds__(256, 2) void qkv_mfma(
    const float* __restrict__ x,
    const float* __restrict__ Wq, const float* __restrict__ bq,
    const float* __restrict__ Wk, const float* __restrict__ bk,
    const float* __restrict__ Wv, const float* __restrict__ bv,
    unsigned short* __restrict__ Qb, unsigned short* __restrict__ Kb,
    unsigned short* __restrict__ VB,
    float* __restrict__ qq, float* __restrict__ kk)
{
    __shared__ float red[4][16];
    const int t = threadIdx.x;
    const int w = t >> 6, l = t & 63, lr = l & 15, lc = l >> 4;
    const int mat = blockIdx.x % 3;
    const int tile = blockIdx.x / 3;
    const int r0 = tile * 16;                 // global seq row (incl. batch)
    const int b = r0 >> 10;
    const int s_in_base = r0 & (SS - 1);

    const float* W    = (mat == 0) ? Wq : (mat == 1) ? Wk : Wv;
    const float* bias = (mat == 0) ? bq : (mat == 1) ? bk : bv;

    // A-frags from x, all 8 d-blocks (reused by 4 col-blocks)
    bf16x8 af[8];
#pragma unroll
    for (int db = 0; db < 8; ++db) {
        const float* xp = x + (size_t)(r0 + lr) * DD + db * 32 + 8 * lc;
        float4 f0 = *(const float4*)(xp);
        float4 f1 = *(const float4*)(xp + 4);
        bf16x8 a;
        a[0] = (short)f2bf(f0.x); a[1] = (short)f2bf(f0.y);
        a[2] = (short)f2bf(f0.z); a[3] = (short)f2bf(f0.w);
        a[4] = (short)f2bf(f1.x); a[5] = (short)f2bf(f1.y);
        a[6] = (short)f2bf(f1.z); a[7] = (short)f2bf(f1.w);
        af[db] = a;
    }

    float nrm[4] = {0.f, 0.f, 0.f, 0.f};

#pragma unroll
    for (int cb = 0; cb < 4; ++cb) {
        const int jb = 64 * w + 16 * cb;
        f32x4 acc = {0.f, 0.f, 0.f, 0.f};
#pragma unroll
        for (int db = 0; db < 8; ++db) {
            const float* wp = W + (size_t)(jb + lr) * DD + db * 32 + 8 * lc;
            float4 f0 = *(const float4*)(wp);
            float4 f1 = *(const float4*)(wp + 4);
            bf16x8 bf;
            bf[0] = (short)f2bf(f0.x); bf[1] = (short)f2bf(f0.y);
            bf[2] = (short)f2bf(f0.z); bf[3] = (short)f2bf(f0.w);
            bf[4] = (short)f2bf(f1.x); bf[5] = (short)f2bf(f1.y);
            bf[6] = (short)f2bf(f1.z); bf[7] = (short)f2bf(f1.w);
            acc = __builtin_amdgcn_mfma_f32_16x16x32_bf16(af[db], bf, acc, 0, 0, 0);
        }
        const float bv_ = bias[jb + lr];
#pragma unroll
        for (int r = 0; r < 4; ++r) {
            const int srow = r0 + lc * 4 + r;     // C/D: row=(l>>4)*4+r, col=l%16
            const float v = acc[r] + bv_;
            const unsigned short h = f2bf(v);
            if (mat == 0) {
                Qb[(size_t)srow * DD + jb + lr] = h;
                const float hv = bf2f(h); nrm[r] += hv * hv;
            } else if (mat == 1) {
                Kb[(size_t)srow * DD + jb + lr] = h;
                const float hv = bf2f(h); nrm[r] += hv * hv;
            } else {
                // VB layout: tile(b, kb32=s/32, db16=d/16) of 1024B;
                // lane (kslot*16 + d%16) holds 8 bf16 for k=kb32*32+kslot*8+jj
                const int s_in = s_in_base + lc * 4 + r;
                const int kb32 = s_in >> 5;
                const int kslot = (s_in >> 3) & 3;
                const int jj = s_in & 7;
                const int db16 = 4 * w + cb;
                const size_t off = ((size_t)((b * 32 + kb32) * 16 + db16) << 9)
                                 + ((kslot * 16 + lr) << 3) + jj;
                VB[off] = h;
            }
        }
    }

    if (mat < 2) {
#pragma unroll
        for (int r = 0; r < 4; ++r) {
            float n = nrm[r];
#pragma unroll
            for (int m = 1; m < 16; m <<= 1) n += __shfl_xor(n, m, 64);
            if (lr == 0) red[w][lc * 4 + r] = n;
        }
        __syncthreads();
        if (t < 16) {
            const float s = red[0][t] + red[1][t] + red[2][t] + red[3][t];
            if (mat == 0) qq[r0 + t] = s;
            else          kk[r0 + t] = s;
        }
    }
}

// ---------------------------------------------------------------------------
// Kernel 2: partial attention via MFMA. grid = 128 qtiles x NCH(8) = 1024
// blocks -> 4 blocks/CU, 16 waves/CU. Block = 16 q-rows x 128-k chunk.
// QK^T: wave w owns k-cols [32w, 32w+32): 2 kbi x 8 db MFMA.
// exp(-dist/16) in (0,1] -> no max pass; chunks combine additively.
// P in LDS bf16 [16][128] XOR-swizzled (PV reads 2-way = free, m136).
// PV: wave w owns d-cols [64w,64w+64): A=P swizzled ds_read_b128, B=VB.
// ---------------------------------------------------------------------------
__global__ __launch_bounds__(256, 4) void attn_part_mfma(
    const unsigned short* __restrict__ Qb, const unsigned short* __restrict__ Kb,
    const unsigned short* __restrict__ VB,
    const float* __restrict__ qq, const float* __restrict__ kk,
    float* __restrict__ Opart, float* __restrict__ esum)
{
    __shared__ unsigned short P_s[16 * KCH];   // 4 KB, XOR-swizzled
    __shared__ float kk_s[KCH];
    __shared__ float qq_s[16];
    __shared__ float es_red[4][16];

    const int t = threadIdx.x;
    const int w = t >> 6, l = t & 63, lr = l & 15, lc = l >> 4;
    const int qtile = blockIdx.x >> 3;
    const int c = blockIdx.x & 7;
    const int rowbase = qtile * 16;            // global row
    const int b = rowbase >> 10;
    const int s0 = c * KCH;                    // chunk start within batch

    if (t < KCH) kk_s[t] = kk[b * SS + s0 + t];
    if (t < 16) qq_s[t] = qq[rowbase + t];

    // Q A-frags: lane(row=l%16, 8 contiguous d), held in regs for the block
    bf16x8 qf[8];
#pragma unroll
    for (int db = 0; db < 8; ++db)
        qf[db] = *(const bf16x8*)(Qb + (size_t)(rowbase + lr) * DD + db * 32 + 8 * lc);

    __syncthreads();

    // ---- QK^T + exp ----
    float psum[4] = {0.f, 0.f, 0.f, 0.f};
#pragma unroll
    for (int kbi = 0; kbi < 2; ++kbi) {
        const int kb = 32 * w + 16 * kbi;
        f32x4 acc = {0.f, 0.f, 0.f, 0.f};
#pragma unroll
        for (int db = 0; db < 8; ++db) {
            bf16x8 kf = *(const bf16x8*)(
                Kb + (size_t)(b * SS + s0 + kb + lr) * DD + db * 32 + 8 * lc);
            acc = __builtin_amdgcn_mfma_f32_16x16x32_bf16(qf[db], kf, acc, 0, 0, 0);
        }
        const int kcol = kb + lr;
        const float kkv = kk_s[kcol];
#pragma unroll
        for (int r = 0; r < 4; ++r) {
            const int qi = lc * 4 + r;
            const float d2 = fmaxf(qq_s[qi] + kkv - 2.f * acc[r], 0.f);
            const float e = __expf(-sqrtf(d2) * 0.0625f);
            psum[r] += e;
            P_s[qi * KCH + (kcol ^ ((qi & 7) << 3))] = f2bf(e);
        }
    }
    // per-row e-sums: reduce across l%16, then across waves via LDS
#pragma unroll
    for (int r = 0; r < 4; ++r) {
        float s = psum[r];
#pragma unroll
        for (int m = 1; m < 16; m <<= 1) s += __shfl_xor(s, m, 64);
        if (lr == 0) es_red[w][lc * 4 + r] = s;
    }
    __syncthreads();
    if (t < 16)
        esum[(size_t)c * (BB * SS) + rowbase + t] =
            es_red[0][t] + es_red[1][t] + es_red[2][t] + es_red[3][t];

    // ---- PV ----
    f32x4 acc2[4];
#pragma unroll
    for (int i = 0; i < 4; ++i) acc2[i] = (f32x4){0.f, 0.f, 0.f, 0.f};

#pragma unroll
    for (int ki = 0; ki < KCH / 32; ++ki) {
        // A = P: lane(row q=l%16, k = 32ki + 8*(l>>4) + j), swizzled read
        bf16x8 pf = *(const bf16x8*)(
            P_s + lr * KCH + ((32 * ki + 8 * lc) ^ ((lr & 7) << 3)));
        const size_t tbase =
            ((size_t)((b * 32 + c * (KCH / 32) + ki) * 16 + 4 * w) << 9) + l * 8;
#pragma unroll
        for (int dbi = 0; dbi < 4; ++dbi) {
            bf16x8 vf = *(const bf16x8*)(VB + tbase + ((size_t)dbi << 9));
            acc2[dbi] = __builtin_amdgcn_mfma_f32_16x16x32_bf16(pf, vf, acc2[dbi], 0, 0, 0);
        }
    }
#pragma unroll
    for (int dbi = 0; dbi < 4; ++dbi)
#pragma unroll
        for (int r = 0; r < 4; ++r)
            Opart[((size_t)c * (BB * SS) + rowbase + lc * 4 + r) * DD
                  + 64 * w + 16 * dbi + lr] = acc2[dbi][r];
}

// ---------------------------------------------------------------------------
// Kernel 3: combine chunks + output projection via MFMA.
// grid = 128 blocks. Block = 16 rows x 256 cols.
// A-frag = (sum_c Opart) * (1/denom) -> bf16 (coalesced 32B/lane fp32 loads).
// B-frag = Wo rows (same pattern as qkv_mfma). 32 MFMA/wave. Bias epilogue.
// ---------------------------------------------------------------------------
__global__ __launch_bounds__(256, 2) void combine_mfma(
    const float* __restrict__ Opart, const float* __restrict__ esum,
    const float* __restrict__ Wo, const float* __restrict__ bo,
    float* __restrict__ out)
{
    __shared__ float inv_s[16];
    const int t = threadIdx.x;
    const int w = t >> 6, l = t & 63, lr = l & 15, lc = l >> 4;
    const int r0 = blockIdx.x * 16;   // global row

    if (t < 16) {
        float d = 0.f;
#pragma unroll
        for (int c = 0; c < NCH; ++c) d += esum[(size_t)c * (BB * SS) + r0 + t];
        inv_s[t] = 1.f / d;
    }
    __syncthreads();

    const float inv = inv_s[lr];
    bf16x8 af[8];
#pragma unroll
    for (int db = 0; db < 8; ++db) {
        const float* op = Opart + (size_t)(r0 + lr) * DD + db * 32 + 8 * lc;
        float s0 = 0.f, s1 = 0.f, s2 = 0.f, s3 = 0.f;
        float s4 = 0.f, s5 = 0.f, s6 = 0.f, s7 = 0.f;
#pragma unroll
        for (int c = 0; c < NCH; ++c) {
            const float* p = op + (size_t)c * ((size_t)BB * SS * DD);
            float4 a0 = *(const float4*)(p);
            float4 a1 = *(const float4*)(p + 4);
            s0 += a0.x; s1 += a0.y; s2 += a0.z; s3 += a0.w;
            s4 += a1.x; s5 += a1.y; s6 += a1.z; s7 += a1.w;
        }
        bf16x8 a;
        a[0] = (short)f2bf(s0 * inv); a[1] = (short)f2bf(s1 * inv);
        a[2] = (short)f2bf(s2 * inv); a[3] = (short)f2bf(s3 * inv);
        a[4] = (short)f2bf(s4 * inv); a[5] = (short)f2bf(s5 * inv);
        a[6] = (short)f2bf(s6 * inv); a[7] = (short)f2bf(s7 * inv);
        af[db] = a;
    }

#pragma unroll
    for (int cb = 0; cb < 4; ++cb) {
        const int jb = 64 * w + 16 * cb;
        f32x4 acc = {0.f, 0.f, 0.f, 0.f};
#pragma unroll
        for (int db = 0; db < 8; ++db) {
            const float* wp = Wo + (size_t)(jb + lr) * DD + db * 32 + 8 * lc;
            float4 f0 = *(const float4*)(wp);
            float4 f1 = *(const float4*)(wp + 4);
            bf16x8 bf;
            bf[0] = (short)f2bf(f0.x); bf[1] = (short)f2bf(f0.y);
            bf[2] = (short)f2bf(f0.z); bf[3] = (short)f2bf(f0.w);
            bf[4] = (short)f2bf(f1.x); bf[5] = (short)f2bf(f1.y);
            bf[6] = (short)f2bf(f1.z); bf[7] = (short)f2bf(f1.w);
            acc = __builtin_amdgcn_mfma_f32_16x16x32_bf16(af[db], bf, acc, 0, 0, 0);
        }
        const float bov = bo[jb + lr];
#pragma unroll
        for (int r = 0; r < 4; ++r)
            out[(size_t)(r0 + lc * 4 + r) * DD + jb + lr] = acc[r] + bov;
    }
}

// ---------------------------------------------------------------------------
extern "C" void kernel_launch(void* const* d_in, const int* in_sizes, int n_in,
                              void* d_out, int out_size, void* d_ws, size_t ws_size,
                              hipStream_t stream) {
    const float* x  = (const float*)d_in[0];
    const float* Wq = (const float*)d_in[1];
    const float* bq = (const float*)d_in[2];
    const float* Wk = (const float*)d_in[3];
    const float* bk = (const float*)d_in[4];
    const float* Wv = (const float*)d_in[5];
    const float* bv = (const float*)d_in[6];
    const float* Wo = (const float*)d_in[7];
    const float* bo = (const float*)d_in[8];
    float* out = (float*)d_out;

    // ws layout: Qb | Kb | VB (bf16) | qq | kk | esum | Opart (fp32)
    const size_t rows = (size_t)BB * SS;            // 2048
    unsigned short* Qb = (unsigned short*)d_ws;
    unsigned short* Kb = Qb + rows * DD;
    unsigned short* VB = Kb + rows * DD;
    float* qq    = (float*)(VB + rows * DD);
    float* kk    = qq + rows;
    float* esum  = kk + rows;
    float* Opart = esum + (size_t)NCH * rows;       // NCH*rows*DD floats

    qkv_mfma<<<(int)(rows / 16) * 3, 256, 0, stream>>>(
        x, Wq, bq, Wk, bk, Wv, bv, Qb, Kb, VB, qq, kk);
    attn_part_mfma<<<(int)(rows / 16) * NCH, 256, 0, stream>>>(
        Qb, Kb, VB, qq, kk, Opart, esum);
    combine_mfma<<<(int)(rows / 16), 256, 0, stream>>>(
        Opart, esum, Wo, bo, out);
}

// Round 6
// 62.323 us; speedup vs baseline: 1.1482x; 1.1482x over previous
//
#include <hip/hip_runtime.h>
#include <hip/hip_bf16.h>

#define BB 2
#define SS 1024
#define DD 256
#define NCH 4           // k-chunks in attn
#define KCH 256         // k-chunk size

typedef __attribute__((ext_vector_type(8))) short bf16x8;
typedef __attribute__((ext_vector_type(4))) float f32x4;

__device__ __forceinline__ unsigned short f2bf(float f) {
    __hip_bfloat16 h = __float2bfloat16(f);
    return *reinterpret_cast<unsigned short*>(&h);
}
__device__ __forceinline__ float bf2f(unsigned short u) {
    __hip_bfloat16 h;
    *reinterpret_cast<unsigned short*>(&h) = u;
    return __bfloat162float(h);
}

// ---------------------------------------------------------------------------
// Kernel 1: QKV projection via MFMA (byte-identical to round 4).
// grid = 128 rowtiles x 3 mats = 384. Block = 16 seq-rows x 256 out-cols.
// ---------------------------------------------------------------------------
__global__ __launch_bounds__(256, 2) void qkv_mfma(
    const float* __restrict__ x,
    const float* __restrict__ Wq, const float* __restrict__ bq,
    const float* __restrict__ Wk, const float* __restrict__ bk,
    const float* __restrict__ Wv, const float* __restrict__ bv,
    unsigned short* __restrict__ Qb, unsigned short* __restrict__ Kb,
    unsigned short* __restrict__ VB,
    float* __restrict__ qq, float* __restrict__ kk)
{
    __shared__ float red[4][16];
    const int t = threadIdx.x;
    const int w = t >> 6, l = t & 63, lr = l & 15, lc = l >> 4;
    const int mat = blockIdx.x % 3;
    const int tile = blockIdx.x / 3;
    const int r0 = tile * 16;                 // global seq row (incl. batch)
    const int b = r0 >> 10;
    const int s_in_base = r0 & (SS - 1);

    const float* W    = (mat == 0) ? Wq : (mat == 1) ? Wk : Wv;
    const float* bias = (mat == 0) ? bq : (mat == 1) ? bk : bv;

    // A-frags from x, all 8 d-blocks (reused by 4 col-blocks)
    bf16x8 af[8];
#pragma unroll
    for (int db = 0; db < 8; ++db) {
        const float* xp = x + (size_t)(r0 + lr) * DD + db * 32 + 8 * lc;
        float4 f0 = *(const float4*)(xp);
        float4 f1 = *(const float4*)(xp + 4);
        bf16x8 a;
        a[0] = (short)f2bf(f0.x); a[1] = (short)f2bf(f0.y);
        a[2] = (short)f2bf(f0.z); a[3] = (short)f2bf(f0.w);
        a[4] = (short)f2bf(f1.x); a[5] = (short)f2bf(f1.y);
        a[6] = (short)f2bf(f1.z); a[7] = (short)f2bf(f1.w);
        af[db] = a;
    }

    float nrm[4] = {0.f, 0.f, 0.f, 0.f};

#pragma unroll
    for (int cb = 0; cb < 4; ++cb) {
        const int jb = 64 * w + 16 * cb;
        f32x4 acc = {0.f, 0.f, 0.f, 0.f};
#pragma unroll
        for (int db = 0; db < 8; ++db) {
            const float* wp = W + (size_t)(jb + lr) * DD + db * 32 + 8 * lc;
            float4 f0 = *(const float4*)(wp);
            float4 f1 = *(const float4*)(wp + 4);
            bf16x8 bf;
            bf[0] = (short)f2bf(f0.x); bf[1] = (short)f2bf(f0.y);
            bf[2] = (short)f2bf(f0.z); bf[3] = (short)f2bf(f0.w);
            bf[4] = (short)f2bf(f1.x); bf[5] = (short)f2bf(f1.y);
            bf[6] = (short)f2bf(f1.z); bf[7] = (short)f2bf(f1.w);
            acc = __builtin_amdgcn_mfma_f32_16x16x32_bf16(af[db], bf, acc, 0, 0, 0);
        }
        const float bv_ = bias[jb + lr];
#pragma unroll
        for (int r = 0; r < 4; ++r) {
            const int srow = r0 + lc * 4 + r;     // C/D: row=(l>>4)*4+r, col=l%16
            const float v = acc[r] + bv_;
            const unsigned short h = f2bf(v);
            if (mat == 0) {
                Qb[(size_t)srow * DD + jb + lr] = h;
                const float hv = bf2f(h); nrm[r] += hv * hv;
            } else if (mat == 1) {
                Kb[(size_t)srow * DD + jb + lr] = h;
                const float hv = bf2f(h); nrm[r] += hv * hv;
            } else {
                // VB layout: tile(b, kb32=s/32, db16=d/16) of 1024B;
                // lane (kslot*16 + d%16) holds 8 bf16 for k=kb32*32+kslot*8+jj
                const int s_in = s_in_base + lc * 4 + r;
                const int kb32 = s_in >> 5;
                const int kslot = (s_in >> 3) & 3;
                const int jj = s_in & 7;
                const int db16 = 4 * w + cb;
                const size_t off = ((size_t)((b * 32 + kb32) * 16 + db16) << 9)
                                 + ((kslot * 16 + lr) << 3) + jj;
                VB[off] = h;
            }
        }
    }

    if (mat < 2) {
#pragma unroll
        for (int r = 0; r < 4; ++r) {
            float n = nrm[r];
#pragma unroll
            for (int m = 1; m < 16; m <<= 1) n += __shfl_xor(n, m, 64);
            if (lr == 0) red[w][lc * 4 + r] = n;
        }
        __syncthreads();
        if (t < 16) {
            const float s = red[0][t] + red[1][t] + red[2][t] + red[3][t];
            if (mat == 0) qq[r0 + t] = s;
            else          kk[r0 + t] = s;
        }
    }
}

// ---------------------------------------------------------------------------
// Kernel 2: partial attention via MFMA (byte-identical to round 4).
// grid = 128 qtiles x NCH(4) = 512 blocks (2/CU). Block = 16 q x 256 k.
// ---------------------------------------------------------------------------
__global__ __launch_bounds__(256, 2) void attn_part_mfma(
    const unsigned short* __restrict__ Qb, const unsigned short* __restrict__ Kb,
    const unsigned short* __restrict__ VB,
    const float* __restrict__ qq, const float* __restrict__ kk,
    float* __restrict__ Opart, float* __restrict__ esum)
{
    __shared__ unsigned short P_s[16 * 256];   // 8 KB, XOR-swizzled
    __shared__ float kk_s[KCH];
    __shared__ float qq_s[16];
    __shared__ float es_red[4][16];

    const int t = threadIdx.x;
    const int w = t >> 6, l = t & 63, lr = l & 15, lc = l >> 4;
    const int qtile = blockIdx.x >> 2;
    const int c = blockIdx.x & 3;
    const int rowbase = qtile * 16;            // global row
    const int b = rowbase >> 10;
    const int s0 = c * KCH;                    // chunk start within batch

    kk_s[t] = kk[b * SS + s0 + t];
    if (t < 16) qq_s[t] = qq[rowbase + t];

    // Q A-frags: lane(row=l%16, 8 contiguous d), held in regs for the block
    bf16x8 qf[8];
#pragma unroll
    for (int db = 0; db < 8; ++db)
        qf[db] = *(const bf16x8*)(Qb + (size_t)(rowbase + lr) * DD + db * 32 + 8 * lc);

    __syncthreads();

    // ---- QK^T + exp ----
    float psum[4] = {0.f, 0.f, 0.f, 0.f};
#pragma unroll
    for (int kbi = 0; kbi < 4; ++kbi) {
        const int kb = 64 * w + 16 * kbi;
        f32x4 acc = {0.f, 0.f, 0.f, 0.f};
#pragma unroll
        for (int db = 0; db < 8; ++db) {
            bf16x8 kf = *(const bf16x8*)(
                Kb + (size_t)(b * SS + s0 + kb + lr) * DD + db * 32 + 8 * lc);
            acc = __builtin_amdgcn_mfma_f32_16x16x32_bf16(qf[db], kf, acc, 0, 0, 0);
        }
        const int kcol = kb + lr;
        const float kkv = kk_s[kcol];
#pragma unroll
        for (int r = 0; r < 4; ++r) {
            const int qi = lc * 4 + r;
            const float d2 = fmaxf(qq_s[qi] + kkv - 2.f * acc[r], 0.f);
            const float e = __expf(-sqrtf(d2) * 0.0625f);
            psum[r] += e;
            P_s[qi * 256 + (kcol ^ ((qi & 7) << 3))] = f2bf(e);
        }
    }
    // per-row e-sums: reduce across l%16, then across waves via LDS
#pragma unroll
    for (int r = 0; r < 4; ++r) {
        float s = psum[r];
#pragma unroll
        for (int m = 1; m < 16; m <<= 1) s += __shfl_xor(s, m, 64);
        if (lr == 0) es_red[w][lc * 4 + r] = s;
    }
    __syncthreads();
    if (t < 16)
        esum[(size_t)c * (BB * SS) + rowbase + t] =
            es_red[0][t] + es_red[1][t] + es_red[2][t] + es_red[3][t];

    // ---- PV ----
    f32x4 acc2[4];
#pragma unroll
    for (int i = 0; i < 4; ++i) acc2[i] = (f32x4){0.f, 0.f, 0.f, 0.f};

#pragma unroll
    for (int ki = 0; ki < 8; ++ki) {
        // A = P: lane(row q=l%16, k = 32ki + 8*(l>>4) + j), swizzled read
        bf16x8 pf = *(const bf16x8*)(
            P_s + lr * 256 + ((32 * ki + 8 * lc) ^ ((lr & 7) << 3)));
        const size_t tbase =
            ((size_t)((b * 32 + c * 8 + ki) * 16 + 4 * w) << 9) + l * 8;
#pragma unroll
        for (int dbi = 0; dbi < 4; ++dbi) {
            bf16x8 vf = *(const bf16x8*)(VB + tbase + ((size_t)dbi << 9));
            acc2[dbi] = __builtin_amdgcn_mfma_f32_16x16x32_bf16(pf, vf, acc2[dbi], 0, 0, 0);
        }
    }
#pragma unroll
    for (int dbi = 0; dbi < 4; ++dbi)
#pragma unroll
        for (int r = 0; r < 4; ++r)
            Opart[((size_t)c * (BB * SS) + rowbase + lc * 4 + r) * DD
                  + 64 * w + 16 * dbi + lr] = acc2[dbi][r];
}

// ---------------------------------------------------------------------------
// Kernel 3: combine + output projection via MFMA, col-split x4.
// grid = 128 qtiles x 4 col-quarters = 512 blocks (2/CU, 8 waves/CU).
// Block = 16 rows x 64 cols; wave w owns 16 cols (jb = 64*ch + 16*w).
// A-frag = (sum_c Opart) * (1/denom) -> bf16; B-frag = Wo rows. 8 MFMA/wave.
// ---------------------------------------------------------------------------
__global__ __launch_bounds__(256, 2) void combine_mfma(
    const float* __restrict__ Opart, const float* __restrict__ esum,
    const float* __restrict__ Wo, const float* __restrict__ bo,
    float* __restrict__ out)
{
    __shared__ float inv_s[16];
    const int t = threadIdx.x;
    const int w = t >> 6, l = t & 63, lr = l & 15, lc = l >> 4;
    const int r0 = (blockIdx.x >> 2) * 16;   // global row
    const int ch = blockIdx.x & 3;           // col quarter

    if (t < 16) {
        float d = 0.f;
#pragma unroll
        for (int c = 0; c < NCH; ++c) d += esum[(size_t)c * (BB * SS) + r0 + t];
        inv_s[t] = 1.f / d;
    }
    __syncthreads();

    const float inv = inv_s[lr];
    bf16x8 af[8];
#pragma unroll
    for (int db = 0; db < 8; ++db) {
        const float* op = Opart + (size_t)(r0 + lr) * DD + db * 32 + 8 * lc;
        float s0 = 0.f, s1 = 0.f, s2 = 0.f, s3 = 0.f;
        float s4 = 0.f, s5 = 0.f, s6 = 0.f, s7 = 0.f;
#pragma unroll
        for (int c = 0; c < NCH; ++c) {
            const float* p = op + (size_t)c * ((size_t)BB * SS * DD);
            float4 a0 = *(const float4*)(p);
            float4 a1 = *(const float4*)(p + 4);
            s0 += a0.x; s1 += a0.y; s2 += a0.z; s3 += a0.w;
            s4 += a1.x; s5 += a1.y; s6 += a1.z; s7 += a1.w;
        }
        bf16x8 a;
        a[0] = (short)f2bf(s0 * inv); a[1] = (short)f2bf(s1 * inv);
        a[2] = (short)f2bf(s2 * inv); a[3] = (short)f2bf(s3 * inv);
        a[4] = (short)f2bf(s4 * inv); a[5] = (short)f2bf(s5 * inv);
        a[6] = (short)f2bf(s6 * inv); a[7] = (short)f2bf(s7 * inv);
        af[db] = a;
    }

    const int jb = 64 * ch + 16 * w;
    f32x4 acc = {0.f, 0.f, 0.f, 0.f};
#pragma unroll
    for (int db = 0; db < 8; ++db) {
        const float* wp = Wo + (size_t)(jb + lr) * DD + db * 32 + 8 * lc;
        float4 f0 = *(const float4*)(wp);
        float4 f1 = *(const float4*)(wp + 4);
        bf16x8 bf;
        bf[0] = (short)f2bf(f0.x); bf[1] = (short)f2bf(f0.y);
        bf[2] = (short)f2bf(f0.z); bf[3] = (short)f2bf(f0.w);
        bf[4] = (short)f2bf(f1.x); bf[5] = (short)f2bf(f1.y);
        bf[6] = (short)f2bf(f1.z); bf[7] = (short)f2bf(f1.w);
        acc = __builtin_amdgcn_mfma_f32_16x16x32_bf16(af[db], bf, acc, 0, 0, 0);
    }
    const float bov = bo[jb + lr];
#pragma unroll
    for (int r = 0; r < 4; ++r)
        out[(size_t)(r0 + lc * 4 + r) * DD + jb + lr] = acc[r] + bov;
}

// ---------------------------------------------------------------------------
extern "C" void kernel_launch(void* const* d_in, const int* in_sizes, int n_in,
                              void* d_out, int out_size, void* d_ws, size_t ws_size,
                              hipStream_t stream) {
    const float* x  = (const float*)d_in[0];
    const float* Wq = (const float*)d_in[1];
    const float* bq = (const float*)d_in[2];
    const float* Wk = (const float*)d_in[3];
    const float* bk = (const float*)d_in[4];
    const float* Wv = (const float*)d_in[5];
    const float* bv = (const float*)d_in[6];
    const float* Wo = (const float*)d_in[7];
    const float* bo = (const float*)d_in[8];
    float* out = (float*)d_out;

    // ws layout: Qb | Kb | VB (bf16) | qq | kk | esum | Opart (fp32)
    const size_t rows = (size_t)BB * SS;            // 2048
    unsigned short* Qb = (unsigned short*)d_ws;
    unsigned short* Kb = Qb + rows * DD;
    unsigned short* VB = Kb + rows * DD;
    float* qq    = (float*)(VB + rows * DD);
    float* kk    = qq + rows;
    float* esum  = kk + rows;
    float* Opart = esum + (size_t)NCH * rows;       // NCH*rows*DD floats

    qkv_mfma<<<(int)(rows / 16) * 3, 256, 0, stream>>>(
        x, Wq, bq, Wk, bk, Wv, bv, Qb, Kb, VB, qq, kk);
    attn_part_mfma<<<(int)(rows / 16) * NCH, 256, 0, stream>>>(
        Qb, Kb, VB, qq, kk, Opart, esum);
    combine_mfma<<<(int)(rows / 16) * 4, 256, 0, stream>>>(
        Opart, esum, Wo, bo, out);
}